// Round 1
// baseline (311.353 us; speedup 1.0000x reference)
//
#include <hip/hip_runtime.h>
#include <math.h>

#define WSZ   11
#define HALO  10
#define TW    32
#define TH    32
#define IN_W  (TW + HALO)   // 42
#define IN_H  (TH + HALO)   // 42
#define IMG_H 512
#define IMG_W 512
#define OUT_H (IMG_H - HALO)  // 502
#define OUT_W (IMG_W - HALO)  // 502
#define NBC   48              // 16*3

// ws layout: bytes [0..3] uint min_key, [4..7] uint max_key, [8..15] double sum

__device__ __forceinline__ unsigned enc_key(float f) {
    unsigned u = __float_as_uint(f);
    return (u & 0x80000000u) ? ~u : (u | 0x80000000u);
}
__device__ __forceinline__ float dec_key(unsigned k) {
    unsigned u = (k & 0x80000000u) ? (k ^ 0x80000000u) : ~k;
    return __uint_as_float(u);
}

__global__ void init_ws(unsigned* wsi, double* wsum) {
    wsi[0] = 0xFFFFFFFFu;  // min key
    wsi[1] = 0u;           // max key
    wsum[0] = 0.0;
}

__global__ __launch_bounds__(256) void minmax_kernel(const float4* __restrict__ x,
                                                     int n4, unsigned* wsi) {
    float lmin = INFINITY, lmax = -INFINITY;
    for (int i = blockIdx.x * blockDim.x + threadIdx.x; i < n4;
         i += gridDim.x * blockDim.x) {
        float4 v = x[i];
        lmin = fminf(lmin, fminf(fminf(v.x, v.y), fminf(v.z, v.w)));
        lmax = fmaxf(lmax, fmaxf(fmaxf(v.x, v.y), fmaxf(v.z, v.w)));
    }
    for (int o = 32; o; o >>= 1) {
        lmin = fminf(lmin, __shfl_xor(lmin, o));
        lmax = fmaxf(lmax, __shfl_xor(lmax, o));
    }
    __shared__ float smin[4], smax[4];
    int tid = threadIdx.x;
    if ((tid & 63) == 0) { smin[tid >> 6] = lmin; smax[tid >> 6] = lmax; }
    __syncthreads();
    if (tid == 0) {
        float m0 = fminf(fminf(smin[0], smin[1]), fminf(smin[2], smin[3]));
        float m1 = fmaxf(fmaxf(smax[0], smax[1]), fmaxf(smax[2], smax[3]));
        atomicMin(&wsi[0], enc_key(m0));
        atomicMax(&wsi[1], enc_key(m1));
    }
}

__global__ __launch_bounds__(256) void ssim_kernel(const float* __restrict__ x,
                                                   const float* __restrict__ y,
                                                   const unsigned* __restrict__ wsi,
                                                   double* wsum) {
    __shared__ float sx[IN_H][IN_W];
    __shared__ float sy[IN_H][IN_W];
    __shared__ float hbuf[5][IN_H][TW];
    __shared__ float gwin[WSZ];
    __shared__ float wpart[4];

    const int tid = threadIdx.x;
    if (tid == 0) {
        // fp64 window, normalized, cast to fp32 (matches NumPy reference)
        double g[WSZ], s = 0.0;
        #pragma unroll
        for (int i = 0; i < WSZ; i++) {
            double d = (double)(i - WSZ / 2);
            g[i] = exp(-(d * d) / (2.0 * 1.5 * 1.5));
            s += g[i];
        }
        #pragma unroll
        for (int i = 0; i < WSZ; i++) gwin[i] = (float)(g[i] / s);
    }

    const int bc  = blockIdx.x;
    const int oy0 = blockIdx.y * TH;
    const int ox0 = blockIdx.z * TW;
    const float* xb = x + (size_t)bc * IMG_H * IMG_W;
    const float* yb = y + (size_t)bc * IMG_H * IMG_W;

    // ---- load input tiles (clamped; clamped rows/cols feed only predicated-out outputs)
    for (int idx = tid; idx < IN_H * IN_W; idx += 256) {
        int r = idx / IN_W, c = idx % IN_W;
        int gy = min(oy0 + r, IMG_H - 1);
        int gx = min(ox0 + c, IMG_W - 1);
        float xv = xb[gy * IMG_W + gx];
        float yv = yb[gy * IMG_W + gx];
        sx[r][c] = xv;
        sy[r][c] = yv;
    }
    __syncthreads();

    // ---- horizontal pass: 5 moment channels, IN_H rows x TW cols
    for (int idx = tid; idx < IN_H * TW; idx += 256) {
        int r = idx >> 5, c = idx & 31;
        float a0 = 0.f, a1 = 0.f, a2 = 0.f, a3 = 0.f, a4 = 0.f;
        #pragma unroll
        for (int k = 0; k < WSZ; k++) {
            float w  = gwin[k];
            float xv = sx[r][c + k];
            float yv = sy[r][c + k];
            a0 += w * xv;
            a1 += w * yv;
            a2 += w * xv * xv;
            a3 += w * yv * yv;
            a4 += w * xv * yv;
        }
        hbuf[0][r][c] = a0;
        hbuf[1][r][c] = a1;
        hbuf[2][r][c] = a2;
        hbuf[3][r][c] = a3;
        hbuf[4][r][c] = a4;
    }
    __syncthreads();

    // ---- constants from global min/max (stream-ordered after minmax_kernel)
    float fmin_v = dec_key(wsi[0]);
    float fmax_v = dec_key(wsi[1]);
    float L  = fmax_v - fmin_v;
    float C1 = 0.01f * L; C1 *= C1;
    float C2 = 0.03f * L; C2 *= C2;

    // ---- vertical pass + SSIM map + local sum
    float lsum = 0.f;
    for (int idx = tid; idx < TH * TW; idx += 256) {
        int r = idx >> 5, c = idx & 31;
        int oy = oy0 + r, ox = ox0 + c;
        if (oy < OUT_H && ox < OUT_W) {
            float m1 = 0.f, m2 = 0.f, e11 = 0.f, e22 = 0.f, e12 = 0.f;
            #pragma unroll
            for (int k = 0; k < WSZ; k++) {
                float w = gwin[k];
                m1  += w * hbuf[0][r + k][c];
                m2  += w * hbuf[1][r + k][c];
                e11 += w * hbuf[2][r + k][c];
                e22 += w * hbuf[3][r + k][c];
                e12 += w * hbuf[4][r + k][c];
            }
            float mu1s = m1 * m1, mu2s = m2 * m2, m12 = m1 * m2;
            float s1  = e11 - mu1s;
            float s2  = e22 - mu2s;
            float s12 = e12 - m12;
            float v1  = 2.f * s12 + C2;
            float v2  = s1 + s2 + C2;
            float num = (2.f * m12 + C1) * v1;
            float den = (mu1s + mu2s + C1) * v2;
            lsum += num / den;
        }
    }

    for (int o = 32; o; o >>= 1) lsum += __shfl_xor(lsum, o);
    if ((tid & 63) == 0) wpart[tid >> 6] = lsum;
    __syncthreads();
    if (tid == 0) {
        double t = (double)wpart[0] + (double)wpart[1] +
                   (double)wpart[2] + (double)wpart[3];
        atomicAdd(wsum, t);
    }
}

__global__ void finalize_kernel(const double* wsum, float* out) {
    const double count = (double)NBC * OUT_H * OUT_W;  // 12,096,192
    out[0] = (float)(-wsum[0] / count);
}

extern "C" void kernel_launch(void* const* d_in, const int* in_sizes, int n_in,
                              void* d_out, int out_size, void* d_ws, size_t ws_size,
                              hipStream_t stream) {
    (void)n_in; (void)out_size; (void)ws_size;
    const float* y_pred = (const float*)d_in[0];
    const float* y_true = (const float*)d_in[1];
    float* out = (float*)d_out;

    unsigned* wsi = (unsigned*)d_ws;
    double* wsum = (double*)((char*)d_ws + 8);

    init_ws<<<1, 1, 0, stream>>>(wsi, wsum);

    int n4 = in_sizes[0] / 4;
    minmax_kernel<<<2048, 256, 0, stream>>>((const float4*)y_pred, n4, wsi);

    dim3 grid(NBC, (OUT_H + TH - 1) / TH, (OUT_W + TW - 1) / TW);  // 48 x 16 x 16
    ssim_kernel<<<grid, 256, 0, stream>>>(y_pred, y_true, wsi, wsum);

    finalize_kernel<<<1, 1, 0, stream>>>(wsum, out);
}

// Round 3
// 249.372 us; speedup vs baseline: 1.2485x; 1.2485x over previous
//
#include <hip/hip_runtime.h>
#include <math.h>

#define IMG   512
#define OUTD  502            // 512 - 10
#define NBC   48             // 16*3
#define TH    64             // output tile rows
#define TW    32             // output tile cols
#define IN_ROWS (TH + 10)    // 74
#define SXW   44             // TW + 10 padded to multiple of 4
#define HBW   32

struct WParams { float w[11]; };

// ws layout: [0..3] uint min_key, [4..7] uint max_key, [8..15] double sum

__device__ __forceinline__ unsigned enc_key(float f) {
    unsigned u = __float_as_uint(f);
    return (u & 0x80000000u) ? ~u : (u | 0x80000000u);
}
__device__ __forceinline__ float dec_key(unsigned k) {
    unsigned u = (k & 0x80000000u) ? (k ^ 0x80000000u) : ~k;
    return __uint_as_float(u);
}

__global__ void init_ws(unsigned* wsi, double* wsum) {
    wsi[0] = 0xFFFFFFFFu;
    wsi[1] = 0u;
    wsum[0] = 0.0;
}

__global__ __launch_bounds__(256) void minmax_kernel(const float4* __restrict__ x,
                                                     int n4, unsigned* wsi) {
    float lmin = INFINITY, lmax = -INFINITY;
    for (int i = blockIdx.x * blockDim.x + threadIdx.x; i < n4;
         i += gridDim.x * blockDim.x) {
        float4 v = x[i];
        lmin = fminf(lmin, fminf(fminf(v.x, v.y), fminf(v.z, v.w)));
        lmax = fmaxf(lmax, fmaxf(fmaxf(v.x, v.y), fmaxf(v.z, v.w)));
    }
    for (int o = 32; o; o >>= 1) {
        lmin = fminf(lmin, __shfl_xor(lmin, o));
        lmax = fmaxf(lmax, __shfl_xor(lmax, o));
    }
    __shared__ float smin[4], smax[4];
    int tid = threadIdx.x;
    if ((tid & 63) == 0) { smin[tid >> 6] = lmin; smax[tid >> 6] = lmax; }
    __syncthreads();
    if (tid == 0) {
        float m0 = fminf(fminf(smin[0], smin[1]), fminf(smin[2], smin[3]));
        float m1 = fmaxf(fmaxf(smax[0], smax[1]), fmaxf(smax[2], smax[3]));
        atomicMin(&wsi[0], enc_key(m0));
        atomicMax(&wsi[1], enc_key(m1));
    }
}

__global__ __launch_bounds__(256) void ssim_kernel(const float* __restrict__ x,
                                                   const float* __restrict__ y,
                                                   const unsigned* __restrict__ wsi,
                                                   double* __restrict__ wsum,
                                                   WParams P) {
    // LDS: 74*44*4*2 + 5*74*32*4 = 26048 + 47360 = 73408 B -> 2 blocks/CU
    __shared__ __align__(16) float sx[IN_ROWS * SXW];
    __shared__ __align__(16) float sy[IN_ROWS * SXW];
    __shared__ __align__(16) float hb[5 * IN_ROWS * HBW];
    __shared__ float wpart[4];

    const int tid = threadIdx.x;
    const int bc  = blockIdx.x;
    const int oy0 = blockIdx.y * TH;
    const int ox0 = blockIdx.z * TW;
    const float* xb = x + (size_t)bc * IMG * IMG;
    const float* yb = y + (size_t)bc * IMG * IMG;

    // ---- stage input tiles as float4 (clamped group starts: out-of-range data
    //      only feeds predicated-out outputs, but stays in-bounds)
    for (int idx = tid; idx < IN_ROWS * 11; idx += 256) {
        int r = idx / 11, g = idx - r * 11;
        int gy = min(oy0 + r, IMG - 1);
        int gx = min(ox0 + 4 * g, IMG - 4);
        float4 vx = *(const float4*)(xb + gy * IMG + gx);
        float4 vy = *(const float4*)(yb + gy * IMG + gx);
        *(float4*)(sx + r * SXW + 4 * g) = vx;
        *(float4*)(sy + r * SXW + 4 * g) = vy;
    }
    __syncthreads();

    // ---- horizontal pass: 4 output cols/thread, share xx/yy/xy products
    for (int idx = tid; idx < IN_ROWS * 8; idx += 256) {
        int r = idx >> 3, g = idx & 7;
        int c = 4 * g;
        const float* rx = sx + r * SXW + c;
        const float* ry = sy + r * SXW + c;
        float xr[16], yr[16];
        #pragma unroll
        for (int q = 0; q < 4; q++) {
            float4 a = *(const float4*)(rx + 4 * q);
            float4 b = *(const float4*)(ry + 4 * q);
            xr[4*q] = a.x; xr[4*q+1] = a.y; xr[4*q+2] = a.z; xr[4*q+3] = a.w;
            yr[4*q] = b.x; yr[4*q+1] = b.y; yr[4*q+2] = b.z; yr[4*q+3] = b.w;
        }
        float xx[14], yy[14], xy[14];
        #pragma unroll
        for (int e = 0; e < 14; e++) {
            xx[e] = xr[e] * xr[e];
            yy[e] = yr[e] * yr[e];
            xy[e] = xr[e] * yr[e];
        }
        float acc[5][4];
        #pragma unroll
        for (int ch = 0; ch < 5; ch++)
            #pragma unroll
            for (int j = 0; j < 4; j++) acc[ch][j] = 0.f;
        #pragma unroll
        for (int k = 0; k < 11; k++) {
            float w = P.w[k];
            #pragma unroll
            for (int j = 0; j < 4; j++) {
                acc[0][j] += w * xr[j + k];
                acc[1][j] += w * yr[j + k];
                acc[2][j] += w * xx[j + k];
                acc[3][j] += w * yy[j + k];
                acc[4][j] += w * xy[j + k];
            }
        }
        #pragma unroll
        for (int ch = 0; ch < 5; ch++) {
            float4 v = make_float4(acc[ch][0], acc[ch][1], acc[ch][2], acc[ch][3]);
            *(float4*)(hb + (ch * IN_ROWS + r) * HBW + c) = v;
        }
    }

    // constants (uniform loads; latency hidden under the barrier)
    float fmin_v = dec_key(wsi[0]);
    float fmax_v = dec_key(wsi[1]);
    float L  = fmax_v - fmin_v;
    float C1 = 0.01f * L; C1 *= C1;
    float C2 = 0.03f * L; C2 *= C2;

    __syncthreads();

    // ---- vertical pass: each thread 4 output rows x 2 cols, 14-row slide
    const int q  = tid & 15;    // column pair
    const int rr = tid >> 4;    // 0..15
    const int r0 = 4 * rr;
    const int c  = 2 * q;

    float2 acc[5][4];
    #pragma unroll
    for (int ch = 0; ch < 5; ch++)
        #pragma unroll
        for (int o = 0; o < 4; o++) { acc[ch][o].x = 0.f; acc[ch][o].y = 0.f; }

    #pragma unroll
    for (int k = 0; k < 14; k++) {
        #pragma unroll
        for (int ch = 0; ch < 5; ch++) {
            float2 v = *(const float2*)(hb + (ch * IN_ROWS + r0 + k) * HBW + c);
            #pragma unroll
            for (int o = 0; o < 4; o++) {
                int t = k - o;
                if (t >= 0 && t <= 10) {
                    acc[ch][o].x += P.w[t] * v.x;
                    acc[ch][o].y += P.w[t] * v.y;
                }
            }
        }
    }

    float lsum = 0.f;
    #pragma unroll
    for (int o = 0; o < 4; o++) {
        int oy = oy0 + r0 + o;
        #pragma unroll
        for (int cc = 0; cc < 2; cc++) {
            int ox = ox0 + c + cc;
            if (oy < OUTD && ox < OUTD) {
                float m1  = cc ? acc[0][o].y : acc[0][o].x;
                float m2  = cc ? acc[1][o].y : acc[1][o].x;
                float e11 = cc ? acc[2][o].y : acc[2][o].x;
                float e22 = cc ? acc[3][o].y : acc[3][o].x;
                float e12 = cc ? acc[4][o].y : acc[4][o].x;
                float m1s = m1 * m1, m2s = m2 * m2, m12 = m1 * m2;
                float v1  = 2.f * (e12 - m12) + C2;
                float v2  = (e11 - m1s) + (e22 - m2s) + C2;
                float num = (2.f * m12 + C1) * v1;
                float den = (m1s + m2s + C1) * v2;
                float rc  = __builtin_amdgcn_rcpf(den);
                rc = rc * (2.f - den * rc);   // one Newton step
                lsum += num * rc;
            }
        }
    }

    for (int o = 32; o; o >>= 1) lsum += __shfl_xor(lsum, o);
    if ((tid & 63) == 0) wpart[tid >> 6] = lsum;
    __syncthreads();
    if (tid == 0) {
        double t = (double)wpart[0] + (double)wpart[1] +
                   (double)wpart[2] + (double)wpart[3];
        atomicAdd(wsum, t);
    }
}

__global__ void finalize_kernel(const double* wsum, float* out) {
    const double count = (double)NBC * OUTD * OUTD;  // 12,096,192
    out[0] = (float)(-wsum[0] / count);
}

extern "C" void kernel_launch(void* const* d_in, const int* in_sizes, int n_in,
                              void* d_out, int out_size, void* d_ws, size_t ws_size,
                              hipStream_t stream) {
    (void)n_in; (void)out_size; (void)ws_size;
    const float* y_pred = (const float*)d_in[0];
    const float* y_true = (const float*)d_in[1];
    float* out = (float*)d_out;

    unsigned* wsi = (unsigned*)d_ws;
    double* wsum = (double*)((char*)d_ws + 8);

    // Gaussian window in fp64, normalized, cast to fp32 — matches NumPy ref
    WParams P;
    {
        double g[11], s = 0.0;
        for (int i = 0; i < 11; i++) {
            double d = (double)(i - 5);
            g[i] = exp(-(d * d) / (2.0 * 1.5 * 1.5));
            s += g[i];
        }
        for (int i = 0; i < 11; i++) P.w[i] = (float)(g[i] / s);
    }

    init_ws<<<1, 1, 0, stream>>>(wsi, wsum);

    int n4 = in_sizes[0] / 4;
    minmax_kernel<<<2048, 256, 0, stream>>>((const float4*)y_pred, n4, wsi);

    dim3 grid(NBC, (OUTD + TH - 1) / TH, (OUTD + TW - 1) / TW);  // 48 x 8 x 16
    ssim_kernel<<<grid, 256, 0, stream>>>(y_pred, y_true, wsi, wsum, P);

    finalize_kernel<<<1, 1, 0, stream>>>(wsum, out);
}